// Round 4
// baseline (261610.254 us; speedup 1.0000x reference)
//
#include <hip/hip_runtime.h>
#include <hip/hip_cooperative_groups.h>

namespace cg = cooperative_groups;

#define TT    1024
#define BB    64
#define NWG   256
#define NTHR  512

// ---------------- ws layout (float offsets): states only ----------------
#define O_AHX0 0               // 2 slots x 64*128
#define O_AHC0 16384           // 64*128
#define O_AHX1 24576           // 2 slots
#define O_AHC1 40960
#define O_FHX0 49152           // 2 slots x 64*512
#define O_FHX1 114688          // 2 slots
#define O_POL0 180224          // 64*2560
#define O_POL1 344064
#define WS_ZERO_END 180224

// ---------------- LDS layout (float offsets) ----------------
// AWX row (q*4+ks): [128 xseg | 128 hseg | 32 a-seg | 32 AU-seg], stride 324
#define L_AWX0 0               // 16*324 = 5184
#define L_AWX1 5184
#define L_FWI0 10368           // 16*132 rows (c4*4+ks)
#define L_FWH0 12480
#define L_FWI1 14592
#define L_FWH1 16704
#define L_PW0  18816           // 20*132
#define L_PW1  21456
#define L_AB0  24096           // 4
#define L_AB1  24100
#define L_FB0  24104
#define L_FB1  24108
#define L_PB0  24112           // 20
#define L_PB1  24132           // 20
#define LDS_F  24152           // 96,608 B

__device__ __forceinline__ float sigm(float x) { return 1.f / (1.f + __expf(-x)); }

// sum over n4 float4 groups: a (global) * w (LDS), 4 independent chains
__device__ __forceinline__ float dot_q(const float* __restrict__ a,
                                       const float* __restrict__ w, int n4) {
  float s0 = 0.f, s1 = 0.f, s2 = 0.f, s3 = 0.f;
  #pragma unroll 8
  for (int k = 0; k < n4; ++k) {
    float4 av = ((const float4*)a)[k];
    float4 wv = ((const float4*)w)[k];
    s0 = fmaf(av.x, wv.x, s0); s1 = fmaf(av.y, wv.y, s1);
    s2 = fmaf(av.z, wv.z, s2); s3 = fmaf(av.w, wv.w, s3);
  }
  return (s0 + s1) + (s2 + s3);
}
__device__ __forceinline__ float dot3_q(const float* __restrict__ a,
                                        const float* __restrict__ p,
                                        const float* __restrict__ w, int n4) {
  float s0 = 0.f, s1 = 0.f, s2 = 0.f, s3 = 0.f;
  #pragma unroll 8
  for (int k = 0; k < n4; ++k) {
    float4 av = ((const float4*)a)[k];
    float4 pv = ((const float4*)p)[k];
    float4 wv = ((const float4*)w)[k];
    s0 = fmaf(av.x * pv.x, wv.x, s0); s1 = fmaf(av.y * pv.y, wv.y, s1);
    s2 = fmaf(av.z * pv.z, wv.z, s2); s3 = fmaf(av.w * pv.w, wv.w, s3);
  }
  return (s0 + s1) + (s2 + s3);
}

struct Params {
  const float* x;
  const float *aW_ih0, *aW_hh0, *ab_ih0, *ab_hh0, *pW0, *pb0, *fW_ih0, *fW_hh0, *fb0;
  const float *aW_ih1, *aW_hh1, *ab_ih1, *ab_hh1, *pW1, *pb1, *fW_ih1, *fW_hh1, *fb1;
  float* out;
  float* ws;
};

__global__ __launch_bounds__(NTHR, 2)
void arnn_kernel(Params p) {
  cg::grid_group grid = cg::this_grid();
  extern __shared__ float lds[];
  const int tid = threadIdx.x;
  const int j   = blockIdx.x >> 1;     // unit 0..127
  const int h   = blockIdx.x & 1;      // batch half
  float* __restrict__ ws = p.ws;

  // ---- preload weight slices (fp32) into LDS, packed by (q|c4, ks) ----
  for (int i = tid; i < 16 * 320; i += NTHR) {
    int rr = i / 320, cc = i - rr * 320;
    int q = rr >> 2, ks = rr & 3;
    size_t lrow = (size_t)(q * 128 + j) * 1152;
    size_t hrow = (size_t)(q * 128 + j) * 128;
    float v0, v1;
    if (cc < 128)      { v0 = p.aW_ih0[lrow + ks*128 + cc];          v1 = p.aW_ih1[lrow + ks*128 + cc]; }
    else if (cc < 256) { v0 = p.aW_ih0[lrow + 512 + ks*128 + cc-128]; v1 = p.aW_ih1[lrow + 512 + ks*128 + cc-128]; }
    else if (cc < 288) { v0 = p.aW_ih0[lrow + 1024 + ks*32 + cc-256]; v1 = p.aW_ih1[lrow + 1024 + ks*32 + cc-256]; }
    else               { v0 = p.aW_hh0[hrow + ks*32 + cc-288];       v1 = p.aW_hh1[hrow + ks*32 + cc-288]; }
    lds[L_AWX0 + rr * 324 + cc] = v0;
    lds[L_AWX1 + rr * 324 + cc] = v1;
  }
  for (int i = tid; i < 16 * 128; i += NTHR) {
    int rr = i >> 7, cc = i & 127, c4 = rr >> 2, ks = rr & 3;
    size_t srow = (size_t)(j * 4 + c4) * 512 + ks * 128 + cc;
    lds[L_FWI0 + rr * 132 + cc] = p.fW_ih0[srow];
    lds[L_FWH0 + rr * 132 + cc] = p.fW_hh0[srow];
    lds[L_FWI1 + rr * 132 + cc] = p.fW_ih1[srow];
    lds[L_FWH1 + rr * 132 + cc] = p.fW_hh1[srow];
  }
  for (int i = tid; i < 20 * 128; i += NTHR) {
    int r = i >> 7, cc = i & 127;
    lds[L_PW0 + r * 132 + cc] = p.pW0[(size_t)(j * 20 + r) * 128 + cc];
    lds[L_PW1 + r * 132 + cc] = p.pW1[(size_t)(j * 20 + r) * 128 + cc];
  }
  if (tid < 4) {
    lds[L_AB0 + tid] = p.ab_ih0[tid * 128 + j] + p.ab_hh0[tid * 128 + j];
    lds[L_AB1 + tid] = p.ab_ih1[tid * 128 + j] + p.ab_hh1[tid * 128 + j];
    lds[L_FB0 + tid] = p.fb0[j * 4 + tid];
    lds[L_FB1 + tid] = p.fb1[j * 4 + tid];
  }
  if (tid < 20) {
    lds[L_PB0 + tid] = p.pb0[j * 20 + tid];
    lds[L_PB1 + tid] = p.pb1[j * 20 + tid];
  }
  for (int i = blockIdx.x * NTHR + tid; i < WS_ZERO_END; i += NWG * NTHR) ws[i] = 0.f;
  __syncthreads();
  grid.sync();

  const int b32 = tid >> 4;          // 0..31
  const int q   = (tid >> 2) & 3;    // gate row / aRNN col-in-4
  const int ks  = tid & 3;           // K quarter
  const int b   = h * 32 + b32;      // global batch
  const int lane = tid & 63;
  const bool cell = (tid & 15) == 0;
  const bool ks0  = (tid & 3) == 0;

  for (int t = 0; t < TT; ++t) {
    const int old = t & 1, nw = old ^ 1;
    float* ahx0_o = ws + O_AHX0 + old * 8192;
    float* ahx0_n = ws + O_AHX0 + nw  * 8192;
    float* ahx1_o = ws + O_AHX1 + old * 8192;
    float* ahx1_n = ws + O_AHX1 + nw  * 8192;
    float* ahc0   = ws + O_AHC0;
    float* ahc1   = ws + O_AHC1;
    float* fhx0_o = ws + O_FHX0 + old * 32768;
    float* fhx0_n = ws + O_FHX0 + nw  * 32768;
    float* fhx1_o = ws + O_FHX1 + old * 32768;
    float* fhx1_n = ws + O_FHX1 + nw  * 32768;
    float* pol0   = ws + O_POL0;
    float* pol1   = ws + O_POL1;
    const float* xt = p.x + (size_t)t * BB * 512;

    // ---- P0: LSTM0 gate partials (K split by 4) ----
    {
      const float* w = lds + L_AWX0 + (q * 4 + ks) * 324;
      float s = dot_q(xt     + b * 512 + ks * 128, w,       32);
      s +=      dot_q(fhx0_o + b * 512 + ks * 128, w + 128, 32);
      s +=      dot_q(ahx1_o + b * 128 + ks * 32,  w + 256, 8);
      s +=      dot_q(ahx0_o + b * 128 + ks * 32,  w + 288, 8);
      s += __shfl_xor(s, 1); s += __shfl_xor(s, 2);
      float gi = __shfl(s, (lane & 48) + 0),  gf = __shfl(s, (lane & 48) + 4);
      float gg = __shfl(s, (lane & 48) + 8),  go = __shfl(s, (lane & 48) + 12);
      if (cell) {
        gi += lds[L_AB0 + 0]; gf += lds[L_AB0 + 1];
        gg += lds[L_AB0 + 2]; go += lds[L_AB0 + 3];
        float c  = ahc0[b * 128 + j];
        float c2 = sigm(gf) * c + sigm(gi) * tanhf(gg);
        ahc0[b * 128 + j]   = c2;
        ahx0_n[b * 128 + j] = sigm(go) * tanhf(c2);
      }
    }
    grid.sync();

    // ---- P1: pol0 rows 20j..20j+19 for 32 batches ----
    for (int idx = tid; idx < 640; idx += NTHR) {
      int r = idx >> 5, bb = h * 32 + (idx & 31);
      pol0[bb * 2560 + j * 20 + r] = lds[L_PB0 + r] +
          dot_q(ahx0_n + bb * 128, lds + L_PW0 + r * 132, 32);
    }
    grid.sync();

    // ---- P2: aRNN0 (c = 4j+q), K split by 4 ----
    {
      const float* wi = lds + L_FWI0 + (q * 4 + ks) * 132;
      const float* wh = lds + L_FWH0 + (q * 4 + ks) * 132;
      const float* pr = pol0 + b * 2560;
      float sig = dot3_q(xt     + b * 512 + ks * 128, pr +        ks * 128, wi, 32);
      float shg = dot3_q(fhx0_o + b * 512 + ks * 128, pr + 512  + ks * 128, wh, 32);
      sig += __shfl_xor(sig, 1); sig += __shfl_xor(sig, 2);
      shg += __shfl_xor(shg, 1); shg += __shfl_xor(shg, 2);
      if (ks0) {
        int c = j * 4 + q;
        float v = tanhf(sig * pr[1024 + c] + lds[L_FB0 + q] * pr[2048 + c] + shg * pr[1536 + c]);
        fhx0_n[b * 512 + c] = v;
      }
    }
    grid.sync();

    // ---- P3: LSTM1 gate partials ----
    {
      const float* w = lds + L_AWX1 + (q * 4 + ks) * 324;
      float s = dot_q(fhx0_n + b * 512 + ks * 128, w,       32);
      s +=      dot_q(fhx1_o + b * 512 + ks * 128, w + 128, 32);
      s +=      dot_q(ahx0_n + b * 128 + ks * 32,  w + 256, 8);
      s +=      dot_q(ahx1_o + b * 128 + ks * 32,  w + 288, 8);
      s += __shfl_xor(s, 1); s += __shfl_xor(s, 2);
      float gi = __shfl(s, (lane & 48) + 0),  gf = __shfl(s, (lane & 48) + 4);
      float gg = __shfl(s, (lane & 48) + 8),  go = __shfl(s, (lane & 48) + 12);
      if (cell) {
        gi += lds[L_AB1 + 0]; gf += lds[L_AB1 + 1];
        gg += lds[L_AB1 + 2]; go += lds[L_AB1 + 3];
        float c  = ahc1[b * 128 + j];
        float c2 = sigm(gf) * c + sigm(gi) * tanhf(gg);
        ahc1[b * 128 + j]   = c2;
        ahx1_n[b * 128 + j] = sigm(go) * tanhf(c2);
      }
    }
    grid.sync();

    // ---- P4: pol1 ----
    for (int idx = tid; idx < 640; idx += NTHR) {
      int r = idx >> 5, bb = h * 32 + (idx & 31);
      pol1[bb * 2560 + j * 20 + r] = lds[L_PB1 + r] +
          dot_q(ahx1_n + bb * 128, lds + L_PW1 + r * 132, 32);
    }
    grid.sync();

    // ---- P5: aRNN1 + output (no trailing barrier: P0' is hazard-free vs P5) ----
    {
      const float* wi = lds + L_FWI1 + (q * 4 + ks) * 132;
      const float* wh = lds + L_FWH1 + (q * 4 + ks) * 132;
      const float* pr = pol1 + b * 2560;
      float sig = dot3_q(fhx0_n + b * 512 + ks * 128, pr +       ks * 128, wi, 32);
      float shg = dot3_q(fhx1_o + b * 512 + ks * 128, pr + 512 + ks * 128, wh, 32);
      sig += __shfl_xor(sig, 1); sig += __shfl_xor(sig, 2);
      shg += __shfl_xor(shg, 1); shg += __shfl_xor(shg, 2);
      if (ks0) {
        int c = j * 4 + q;
        float v = tanhf(sig * pr[1024 + c] + lds[L_FB1 + q] * pr[2048 + c] + shg * pr[1536 + c]);
        fhx1_n[b * 512 + c] = v;
        p.out[((size_t)t * BB + b) * 512 + c] = v;
      }
    }
    // no grid.sync() here — P0(t+1) neither reads P5 outputs nor writes P5 inputs
  }
}

extern "C" void kernel_launch(void* const* d_in, const int* in_sizes, int n_in,
                              void* d_out, int out_size, void* d_ws, size_t ws_size,
                              hipStream_t stream) {
  Params prm;
  prm.x      = (const float*)d_in[0];
  prm.aW_ih0 = (const float*)d_in[1];
  prm.aW_hh0 = (const float*)d_in[2];
  prm.ab_ih0 = (const float*)d_in[3];
  prm.ab_hh0 = (const float*)d_in[4];
  prm.pW0    = (const float*)d_in[5];
  prm.pb0    = (const float*)d_in[6];
  prm.fW_ih0 = (const float*)d_in[7];
  prm.fW_hh0 = (const float*)d_in[8];
  prm.fb0    = (const float*)d_in[9];
  prm.aW_ih1 = (const float*)d_in[10];
  prm.aW_hh1 = (const float*)d_in[11];
  prm.ab_ih1 = (const float*)d_in[12];
  prm.ab_hh1 = (const float*)d_in[13];
  prm.pW1    = (const float*)d_in[14];
  prm.pb1    = (const float*)d_in[15];
  prm.fW_ih1 = (const float*)d_in[16];
  prm.fW_hh1 = (const float*)d_in[17];
  prm.fb1    = (const float*)d_in[18];
  prm.out    = (float*)d_out;
  prm.ws     = (float*)d_ws;

  static int lds_bytes = LDS_F * 4;
  hipFuncSetAttribute((const void*)arnn_kernel,
                      hipFuncAttributeMaxDynamicSharedMemorySize, lds_bytes);

  void* kargs[] = { (void*)&prm };
  hipLaunchCooperativeKernel((const void*)arnn_kernel, dim3(NWG), dim3(NTHR),
                             kargs, lds_bytes, stream);
}

// Round 5
// 161428.406 us; speedup vs baseline: 1.6206x; 1.6206x over previous
//
#include <hip/hip_runtime.h>

#define TT    1024
#define BB    64
#define NWG   256
#define NTHR  512

// ---------------- ws layout (float offsets): states only ----------------
#define O_AHX0 0               // 2 slots x 64*128
#define O_AHC0 16384           // 64*128
#define O_AHX1 24576           // 2 slots
#define O_AHC1 40960
#define O_FHX0 49152           // 2 slots x 64*512
#define O_FHX1 114688          // 2 slots
#define O_POL0 180224          // 64*2560
#define O_POL1 344064
#define WS_ZERO_END 180224
#define O_BAR  507904          // barrier block (ints), 8 KB, zeroed by hipMemsetAsync

// barrier layout (int offsets within bar block)
#define BAR_GRPS 16
#define BAR_WPG  16            // NWG / BAR_GRPS
#define BI_ROOT  1024
#define BI_EPOCH 1040

// ---------------- LDS layout (float offsets) ----------------
// AWX row (q*4+ks): [128 xseg | 128 hseg | 32 a-seg | 32 AU-seg], stride 324
#define L_AWX0 0               // 16*324
#define L_AWX1 5184
#define L_FWI0 10368           // 16*132 rows (c4*4+ks)
#define L_FWH0 12480
#define L_FWI1 14592
#define L_FWH1 16704
#define L_PW0  18816           // 20*132
#define L_PW1  21456
#define L_AB0  24096
#define L_AB1  24100
#define L_FB0  24104
#define L_FB1  24108
#define L_PB0  24112
#define L_PB1  24132
#define LDS_F  24152           // 96,608 B

__device__ __forceinline__ float sigm(float x) { return 1.f / (1.f + __expf(-x)); }

__device__ __forceinline__ float dot_q(const float* __restrict__ a,
                                       const float* __restrict__ w, int n4) {
  float s0 = 0.f, s1 = 0.f, s2 = 0.f, s3 = 0.f;
  #pragma unroll 8
  for (int k = 0; k < n4; ++k) {
    float4 av = ((const float4*)a)[k];
    float4 wv = ((const float4*)w)[k];
    s0 = fmaf(av.x, wv.x, s0); s1 = fmaf(av.y, wv.y, s1);
    s2 = fmaf(av.z, wv.z, s2); s3 = fmaf(av.w, wv.w, s3);
  }
  return (s0 + s1) + (s2 + s3);
}
__device__ __forceinline__ float dot3_q(const float* __restrict__ a,
                                        const float* __restrict__ p,
                                        const float* __restrict__ w, int n4) {
  float s0 = 0.f, s1 = 0.f, s2 = 0.f, s3 = 0.f;
  #pragma unroll 8
  for (int k = 0; k < n4; ++k) {
    float4 av = ((const float4*)a)[k];
    float4 pv = ((const float4*)p)[k];
    float4 wv = ((const float4*)w)[k];
    s0 = fmaf(av.x * pv.x, wv.x, s0); s1 = fmaf(av.y * pv.y, wv.y, s1);
    s2 = fmaf(av.z * pv.z, wv.z, s2); s3 = fmaf(av.w * pv.w, wv.w, s3);
  }
  return (s0 + s1) + (s2 + s3);
}

// ---- 2-level grid barrier, monotonic epochs, split arrive/wait ----
__device__ __forceinline__ void bar_arrive(int* bar, int e, int tid, int wgid) {
  __syncthreads();                         // all waves' stores issued (vmcnt drained per-wave)
  if (tid == 0) {
    int g = wgid & (BAR_GRPS - 1);         // same low bits -> same XCD coset
    int old = __hip_atomic_fetch_add(&bar[g * 64], 1,
                                     __ATOMIC_ACQ_REL, __HIP_MEMORY_SCOPE_AGENT);
    if (old == e * BAR_WPG - 1) {          // last of group for this epoch
      int rold = __hip_atomic_fetch_add(&bar[BI_ROOT], 1,
                                        __ATOMIC_ACQ_REL, __HIP_MEMORY_SCOPE_AGENT);
      if (rold == e * BAR_GRPS - 1) {      // last group overall
        __hip_atomic_store(&bar[BI_EPOCH], e,
                           __ATOMIC_RELEASE, __HIP_MEMORY_SCOPE_AGENT);
      }
    }
  }
}
__device__ __forceinline__ void bar_wait(int* bar, int e, int tid) {
  if (tid == 0) {
    while (__hip_atomic_load(&bar[BI_EPOCH], __ATOMIC_RELAXED,
                             __HIP_MEMORY_SCOPE_AGENT) < e)
      __builtin_amdgcn_s_sleep(1);
    (void)__hip_atomic_load(&bar[BI_EPOCH], __ATOMIC_ACQUIRE,
                            __HIP_MEMORY_SCOPE_AGENT);   // buffer_inv: see fresh data
  }
  __syncthreads();
}

struct Params {
  const float* x;
  const float *aW_ih0, *aW_hh0, *ab_ih0, *ab_hh0, *pW0, *pb0, *fW_ih0, *fW_hh0, *fb0;
  const float *aW_ih1, *aW_hh1, *ab_ih1, *ab_hh1, *pW1, *pb1, *fW_ih1, *fW_hh1, *fb1;
  float* out;
  float* ws;
};

__global__ __launch_bounds__(NTHR, 1)
void arnn_kernel(Params p) {
  extern __shared__ float lds[];
  const int tid  = threadIdx.x;
  const int wgid = blockIdx.x;
  const int j    = wgid >> 1;          // unit 0..127
  const int h    = wgid & 1;           // batch half
  float* __restrict__ ws = p.ws;
  int* bar = (int*)(ws + O_BAR);

  // ---- preload weight slices (fp32) into LDS, packed by (q|c4, ks) ----
  for (int i = tid; i < 16 * 320; i += NTHR) {
    int rr = i / 320, cc = i - rr * 320;
    int q = rr >> 2, ks = rr & 3;
    size_t lrow = (size_t)(q * 128 + j) * 1152;
    size_t hrow = (size_t)(q * 128 + j) * 128;
    float v0, v1;
    if (cc < 128)      { v0 = p.aW_ih0[lrow + ks*128 + cc];           v1 = p.aW_ih1[lrow + ks*128 + cc]; }
    else if (cc < 256) { v0 = p.aW_ih0[lrow + 512 + ks*128 + cc-128]; v1 = p.aW_ih1[lrow + 512 + ks*128 + cc-128]; }
    else if (cc < 288) { v0 = p.aW_ih0[lrow + 1024 + ks*32 + cc-256]; v1 = p.aW_ih1[lrow + 1024 + ks*32 + cc-256]; }
    else               { v0 = p.aW_hh0[hrow + ks*32 + cc-288];        v1 = p.aW_hh1[hrow + ks*32 + cc-288]; }
    lds[L_AWX0 + rr * 324 + cc] = v0;
    lds[L_AWX1 + rr * 324 + cc] = v1;
  }
  for (int i = tid; i < 16 * 128; i += NTHR) {
    int rr = i >> 7, cc = i & 127, c4 = rr >> 2, ks = rr & 3;
    size_t srow = (size_t)(j * 4 + c4) * 512 + ks * 128 + cc;
    lds[L_FWI0 + rr * 132 + cc] = p.fW_ih0[srow];
    lds[L_FWH0 + rr * 132 + cc] = p.fW_hh0[srow];
    lds[L_FWI1 + rr * 132 + cc] = p.fW_ih1[srow];
    lds[L_FWH1 + rr * 132 + cc] = p.fW_hh1[srow];
  }
  for (int i = tid; i < 20 * 128; i += NTHR) {
    int r = i >> 7, cc = i & 127;
    lds[L_PW0 + r * 132 + cc] = p.pW0[(size_t)(j * 20 + r) * 128 + cc];
    lds[L_PW1 + r * 132 + cc] = p.pW1[(size_t)(j * 20 + r) * 128 + cc];
  }
  if (tid < 4) {
    lds[L_AB0 + tid] = p.ab_ih0[tid * 128 + j] + p.ab_hh0[tid * 128 + j];
    lds[L_AB1 + tid] = p.ab_ih1[tid * 128 + j] + p.ab_hh1[tid * 128 + j];
    lds[L_FB0 + tid] = p.fb0[j * 4 + tid];
    lds[L_FB1 + tid] = p.fb1[j * 4 + tid];
  }
  if (tid < 20) {
    lds[L_PB0 + tid] = p.pb0[j * 20 + tid];
    lds[L_PB1 + tid] = p.pb1[j * 20 + tid];
  }
  for (int i = wgid * NTHR + tid; i < WS_ZERO_END; i += NWG * NTHR) ws[i] = 0.f;

  int e = 1;
  bar_arrive(bar, e, tid, wgid);
  bar_wait(bar, e, tid);

  const int b32 = tid >> 4;
  const int q   = (tid >> 2) & 3;
  const int ks  = tid & 3;
  const int b   = h * 32 + b32;
  const int lane = tid & 63;
  const bool cell = (tid & 15) == 0;
  const bool ks0  = (tid & 3) == 0;

  // initial pre0 for t=0 (states are zero, x(0) known)
  const float* w0r = lds + L_AWX0 + (q * 4 + ks) * 324;
  const float* w1r = lds + L_AWX1 + (q * 4 + ks) * 324;
  float pre0;
  {
    const float* xt0 = p.x;
    float s = dot_q(xt0 + b * 512 + ks * 128, w0r, 32);
    s += dot_q(ws + O_FHX0 + b * 512 + ks * 128, w0r + 128, 32);
    s += dot_q(ws + O_AHX0 + b * 128 + ks * 32,  w0r + 288, 8);
    pre0 = s;
  }

  for (int t = 0; t < TT; ++t) {
    const int old = t & 1, nw = old ^ 1;
    float* ahx0_o = ws + O_AHX0 + old * 8192;
    float* ahx0_n = ws + O_AHX0 + nw  * 8192;
    float* ahx1_o = ws + O_AHX1 + old * 8192;
    float* ahx1_n = ws + O_AHX1 + nw  * 8192;
    float* ahc0   = ws + O_AHC0;
    float* ahc1   = ws + O_AHC1;
    float* fhx0_o = ws + O_FHX0 + old * 32768;
    float* fhx0_n = ws + O_FHX0 + nw  * 32768;
    float* fhx1_o = ws + O_FHX1 + old * 32768;
    float* fhx1_n = ws + O_FHX1 + nw  * 32768;
    float* pol0   = ws + O_POL0;
    float* pol1   = ws + O_POL1;
    const float* xt = p.x + (size_t)t * BB * 512;

    // ---- P0: LSTM0 residual (ahx1 part) + gate finish ----
    {
      float s = pre0 + dot_q(ahx1_o + b * 128 + ks * 32, w0r + 256, 8);
      s += __shfl_xor(s, 1); s += __shfl_xor(s, 2);
      float gi = __shfl(s, (lane & 48) + 0),  gf = __shfl(s, (lane & 48) + 4);
      float gg = __shfl(s, (lane & 48) + 8),  go = __shfl(s, (lane & 48) + 12);
      if (cell) {
        gi += lds[L_AB0 + 0]; gf += lds[L_AB0 + 1];
        gg += lds[L_AB0 + 2]; go += lds[L_AB0 + 3];
        float c  = ahc0[b * 128 + j];
        float c2 = sigm(gf) * c + sigm(gi) * tanhf(gg);
        ahc0[b * 128 + j]   = c2;
        ahx0_n[b * 128 + j] = sigm(go) * tanhf(c2);
      }
    }
    ++e; bar_arrive(bar, e, tid, wgid); bar_wait(bar, e, tid);   // B1

    // ---- P1: pol0 rows 20j..20j+19 ----
    for (int idx = tid; idx < 640; idx += NTHR) {
      int r = idx >> 5, bb = h * 32 + (idx & 31);
      pol0[bb * 2560 + j * 20 + r] = lds[L_PB0 + r] +
          dot_q(ahx0_n + bb * 128, lds + L_PW0 + r * 132, 32);
    }
    ++e; bar_arrive(bar, e, tid, wgid); bar_wait(bar, e, tid);   // B2

    // ---- P2: aRNN0 ----
    {
      const float* wi = lds + L_FWI0 + (q * 4 + ks) * 132;
      const float* wh = lds + L_FWH0 + (q * 4 + ks) * 132;
      const float* pr = pol0 + b * 2560;
      float sig = dot3_q(xt     + b * 512 + ks * 128, pr +       ks * 128, wi, 32);
      float shg = dot3_q(fhx0_o + b * 512 + ks * 128, pr + 512 + ks * 128, wh, 32);
      sig += __shfl_xor(sig, 1); sig += __shfl_xor(sig, 2);
      shg += __shfl_xor(shg, 1); shg += __shfl_xor(shg, 2);
      if (ks0) {
        int c = j * 4 + q;
        float v = tanhf(sig * pr[1024 + c] + lds[L_FB0 + q] * pr[2048 + c] + shg * pr[1536 + c]);
        fhx0_n[b * 512 + c] = v;
      }
    }
    ++e; bar_arrive(bar, e, tid, wgid);                          // B3 arrive
    // window: LSTM1 partials independent of P2 (fhx1_o, ahx0_n, ahx1_o all synced earlier)
    float pre3;
    {
      float s = dot_q(fhx1_o + b * 512 + ks * 128, w1r + 128, 32);
      s += dot_q(ahx0_n + b * 128 + ks * 32, w1r + 256, 8);
      s += dot_q(ahx1_o + b * 128 + ks * 32, w1r + 288, 8);
      pre3 = s;
    }
    bar_wait(bar, e, tid);                                       // B3 wait

    // ---- P3: LSTM1 residual (fhx0_n part) + gate finish ----
    {
      float s = pre3 + dot_q(fhx0_n + b * 512 + ks * 128, w1r, 32);
      s += __shfl_xor(s, 1); s += __shfl_xor(s, 2);
      float gi = __shfl(s, (lane & 48) + 0),  gf = __shfl(s, (lane & 48) + 4);
      float gg = __shfl(s, (lane & 48) + 8),  go = __shfl(s, (lane & 48) + 12);
      if (cell) {
        gi += lds[L_AB1 + 0]; gf += lds[L_AB1 + 1];
        gg += lds[L_AB1 + 2]; go += lds[L_AB1 + 3];
        float c  = ahc1[b * 128 + j];
        float c2 = sigm(gf) * c + sigm(gi) * tanhf(gg);
        ahc1[b * 128 + j]   = c2;
        ahx1_n[b * 128 + j] = sigm(go) * tanhf(c2);
      }
    }
    ++e; bar_arrive(bar, e, tid, wgid); bar_wait(bar, e, tid);   // B4

    // ---- P4: pol1 ----
    for (int idx = tid; idx < 640; idx += NTHR) {
      int r = idx >> 5, bb = h * 32 + (idx & 31);
      pol1[bb * 2560 + j * 20 + r] = lds[L_PB1 + r] +
          dot_q(ahx1_n + bb * 128, lds + L_PW1 + r * 132, 32);
    }
    ++e; bar_arrive(bar, e, tid, wgid);                          // B5 arrive
    // window: next step's LSTM0 partials (x(t+1), fhx0_n(t)=fhx0_o(t+1), ahx0_n(t)=ahx0_o(t+1))
    if (t + 1 < TT) {
      const float* xn = p.x + (size_t)(t + 1) * BB * 512;
      float s = dot_q(xn + b * 512 + ks * 128, w0r, 32);
      s += dot_q(fhx0_n + b * 512 + ks * 128, w0r + 128, 32);
      s += dot_q(ahx0_n + b * 128 + ks * 32,  w0r + 288, 8);
      pre0 = s;
    }
    bar_wait(bar, e, tid);                                       // B5 wait

    // ---- P5: aRNN1 + output (no trailing barrier; P0(t+1) is hazard-free vs P5) ----
    {
      const float* wi = lds + L_FWI1 + (q * 4 + ks) * 132;
      const float* wh = lds + L_FWH1 + (q * 4 + ks) * 132;
      const float* pr = pol1 + b * 2560;
      float sig = dot3_q(fhx0_n + b * 512 + ks * 128, pr +       ks * 128, wi, 32);
      float shg = dot3_q(fhx1_o + b * 512 + ks * 128, pr + 512 + ks * 128, wh, 32);
      sig += __shfl_xor(sig, 1); sig += __shfl_xor(sig, 2);
      shg += __shfl_xor(shg, 1); shg += __shfl_xor(shg, 2);
      if (ks0) {
        int c = j * 4 + q;
        float v = tanhf(sig * pr[1024 + c] + lds[L_FB1 + q] * pr[2048 + c] + shg * pr[1536 + c]);
        fhx1_n[b * 512 + c] = v;
        p.out[((size_t)t * BB + b) * 512 + c] = v;
      }
    }
  }
}

extern "C" void kernel_launch(void* const* d_in, const int* in_sizes, int n_in,
                              void* d_out, int out_size, void* d_ws, size_t ws_size,
                              hipStream_t stream) {
  Params prm;
  prm.x      = (const float*)d_in[0];
  prm.aW_ih0 = (const float*)d_in[1];
  prm.aW_hh0 = (const float*)d_in[2];
  prm.ab_ih0 = (const float*)d_in[3];
  prm.ab_hh0 = (const float*)d_in[4];
  prm.pW0    = (const float*)d_in[5];
  prm.pb0    = (const float*)d_in[6];
  prm.fW_ih0 = (const float*)d_in[7];
  prm.fW_hh0 = (const float*)d_in[8];
  prm.fb0    = (const float*)d_in[9];
  prm.aW_ih1 = (const float*)d_in[10];
  prm.aW_hh1 = (const float*)d_in[11];
  prm.ab_ih1 = (const float*)d_in[12];
  prm.ab_hh1 = (const float*)d_in[13];
  prm.pW1    = (const float*)d_in[14];
  prm.pb1    = (const float*)d_in[15];
  prm.fW_ih1 = (const float*)d_in[16];
  prm.fW_hh1 = (const float*)d_in[17];
  prm.fb1    = (const float*)d_in[18];
  prm.out    = (float*)d_out;
  prm.ws     = (float*)d_ws;

  // zero the barrier block (counters + epoch) before each run
  hipMemsetAsync((char*)d_ws + (size_t)O_BAR * 4, 0, 8192, stream);

  static int lds_bytes = LDS_F * 4;
  hipFuncSetAttribute((const void*)arnn_kernel,
                      hipFuncAttributeMaxDynamicSharedMemorySize, lds_bytes);

  void* kargs[] = { (void*)&prm };
  hipLaunchCooperativeKernel((const void*)arnn_kernel, dim3(NWG), dim3(NTHR),
                             kargs, lds_bytes, stream);
}

// Round 10
// 156753.149 us; speedup vs baseline: 1.6689x; 1.0298x over previous
//
#include <hip/hip_runtime.h>

#define TT    1024
#define NTHR  512
#define NWG   256

// ---------------- ws layout (float offsets): states only ----------------
#define O_AHX0 0               // 2 slots x 64*128
#define O_AHC0 16384           // 64*128
#define O_AHX1 24576           // 2 slots
#define O_AHC1 40960
#define O_FHX0 49152           // 2 slots x 64*512
#define O_FHX1 114688          // 2 slots
#define O_POL0 180224          // 64*2560
#define O_POL1 344064
#define WS_ZERO_END 507904     // zero states AND pol scratch
#define O_BAR  507904          // barrier ints, 16 KB, zeroed by hipMemsetAsync

// barrier int offsets: group arrive g*64 (g=0..15), root 1024, root-epoch 1088,
// per-group epoch lines 1280+g*64
#define BI_ROOT   1024
#define BI_REPOCH 1088
#define BI_GEPOCH 1280

// ---------------- LDS layout (float offsets) ----------------
// AWX row (q*4+ks): [128 xseg | 128 hseg | 32 a-seg | 32 AU-seg], stride 324
#define L_AWX0 0               // 16*324
#define L_AWX1 5184
#define L_FWI0 10368           // 16*132 rows (c4*4+ks)
#define L_FWH0 12480
#define L_FWI1 14592
#define L_FWH1 16704
#define L_PW0  18816           // 20*132
#define L_PW1  21456
#define L_AB0  24096
#define L_AB1  24100
#define L_FB0  24104
#define L_FB1  24108
#define L_PB0  24112
#define L_PB1  24132
#define LDS_F  24152           // 96,608 B

__device__ __forceinline__ float sigm(float x) { return 1.f / (1.f + __expf(-x)); }

__device__ __forceinline__ float dot_q(const float* __restrict__ a,
                                       const float* __restrict__ w, int n4) {
  float s0 = 0.f, s1 = 0.f, s2 = 0.f, s3 = 0.f;
  #pragma unroll 8
  for (int k = 0; k < n4; ++k) {
    float4 av = ((const float4*)a)[k];
    float4 wv = ((const float4*)w)[k];
    s0 = fmaf(av.x, wv.x, s0); s1 = fmaf(av.y, wv.y, s1);
    s2 = fmaf(av.z, wv.z, s2); s3 = fmaf(av.w, wv.w, s3);
  }
  return (s0 + s1) + (s2 + s3);
}
__device__ __forceinline__ float dot3_q(const float* __restrict__ a,
                                        const float* __restrict__ p,
                                        const float* __restrict__ w, int n4) {
  float s0 = 0.f, s1 = 0.f, s2 = 0.f, s3 = 0.f;
  #pragma unroll 8
  for (int k = 0; k < n4; ++k) {
    float4 av = ((const float4*)a)[k];
    float4 pv = ((const float4*)p)[k];
    float4 wv = ((const float4*)w)[k];
    s0 = fmaf(av.x * pv.x, wv.x, s0); s1 = fmaf(av.y * pv.y, wv.y, s1);
    s2 = fmaf(av.z * pv.z, wv.z, s2); s3 = fmaf(av.w * pv.w, wv.w, s3);
  }
  return (s0 + s1) + (s2 + s3);
}

// ---- 2-level grid barrier (R5-proven arrive) + fan-out wakeup tree ----
__device__ __forceinline__ void bar_arrive(int* bar, int e, int tid, int wid) {
  __syncthreads();
  if (tid == 0) {
    int g = wid & 15;
    int old = __hip_atomic_fetch_add(&bar[g * 64], 1,
                                     __ATOMIC_ACQ_REL, __HIP_MEMORY_SCOPE_AGENT);
    if (old == e * 16 - 1) {          // last of group for this epoch
      int rold = __hip_atomic_fetch_add(&bar[BI_ROOT], 1,
                                        __ATOMIC_ACQ_REL, __HIP_MEMORY_SCOPE_AGENT);
      if (rold == e * 16 - 1) {       // last group overall
        __hip_atomic_store(&bar[BI_REPOCH], e,
                           __ATOMIC_RELEASE, __HIP_MEMORY_SCOPE_AGENT);
      }
    }
  }
}
// leaders (wid<16): poll root epoch, acquire, publish group epoch (release).
// members: poll own group line (<=16 pollers/line), acquire.
__device__ __forceinline__ void bar_wait(int* bar, int e, int tid, int wid) {
  if (tid == 0) {
    if (wid < 16) {
      while (__hip_atomic_load(&bar[BI_REPOCH], __ATOMIC_RELAXED,
                               __HIP_MEMORY_SCOPE_AGENT) < e)
        __builtin_amdgcn_s_sleep(1);
      (void)__hip_atomic_load(&bar[BI_REPOCH], __ATOMIC_ACQUIRE,
                              __HIP_MEMORY_SCOPE_AGENT);
      __hip_atomic_store(&bar[BI_GEPOCH + wid * 64], e,
                         __ATOMIC_RELEASE, __HIP_MEMORY_SCOPE_AGENT);
    } else {
      int g = wid & 15;
      while (__hip_atomic_load(&bar[BI_GEPOCH + g * 64], __ATOMIC_RELAXED,
                               __HIP_MEMORY_SCOPE_AGENT) < e)
        __builtin_amdgcn_s_sleep(1);
      (void)__hip_atomic_load(&bar[BI_GEPOCH + g * 64], __ATOMIC_ACQUIRE,
                              __HIP_MEMORY_SCOPE_AGENT);
    }
  }
  __syncthreads();
}

struct Params {
  const float* x;
  const float *aW_ih0, *aW_hh0, *ab_ih0, *ab_hh0, *pW0, *pb0, *fW_ih0, *fW_hh0, *fb0;
  const float *aW_ih1, *aW_hh1, *ab_ih1, *ab_hh1, *pW1, *pb1, *fW_ih1, *fW_hh1, *fb1;
  float* out;
  float* ws;
};

__global__ __launch_bounds__(NTHR, 1)
void arnn_kernel(Params p) {
  extern __shared__ float lds[];
  const int tid  = threadIdx.x;
  const int wgid = blockIdx.x;
  const int j    = wgid >> 1;          // unit 0..127
  const int h    = wgid & 1;           // batch half
  float* __restrict__ ws = p.ws;
  int* bar = (int*)(ws + O_BAR);

  // ---- preload weight slices (fp32) into LDS, packed by (q|c4, ks) ----
  for (int i = tid; i < 16 * 320; i += NTHR) {
    int rr = i / 320, cc = i - rr * 320;
    int q = rr >> 2, ks = rr & 3;
    size_t lrow = (size_t)(q * 128 + j) * 1152;
    size_t hrow = (size_t)(q * 128 + j) * 128;
    float v0, v1;
    if (cc < 128)      { v0 = p.aW_ih0[lrow + ks*128 + cc];           v1 = p.aW_ih1[lrow + ks*128 + cc]; }
    else if (cc < 256) { v0 = p.aW_ih0[lrow + 512 + ks*128 + cc-128]; v1 = p.aW_ih1[lrow + 512 + ks*128 + cc-128]; }
    else if (cc < 288) { v0 = p.aW_ih0[lrow + 1024 + ks*32 + cc-256]; v1 = p.aW_ih1[lrow + 1024 + ks*32 + cc-256]; }
    else               { v0 = p.aW_hh0[hrow + ks*32 + cc-288];        v1 = p.aW_hh1[hrow + ks*32 + cc-288]; }
    lds[L_AWX0 + rr * 324 + cc] = v0;
    lds[L_AWX1 + rr * 324 + cc] = v1;
  }
  for (int i = tid; i < 16 * 128; i += NTHR) {
    int rr = i >> 7, cc = i & 127, c4 = rr >> 2, ks = rr & 3;
    size_t srow = (size_t)(j * 4 + c4) * 512 + ks * 128 + cc;
    lds[L_FWI0 + rr * 132 + cc] = p.fW_ih0[srow];
    lds[L_FWH0 + rr * 132 + cc] = p.fW_hh0[srow];
    lds[L_FWI1 + rr * 132 + cc] = p.fW_ih1[srow];
    lds[L_FWH1 + rr * 132 + cc] = p.fW_hh1[srow];
  }
  for (int i = tid; i < 20 * 128; i += NTHR) {
    int r = i >> 7, cc = i & 127;
    lds[L_PW0 + r * 132 + cc] = p.pW0[(size_t)(j * 20 + r) * 128 + cc];
    lds[L_PW1 + r * 132 + cc] = p.pW1[(size_t)(j * 20 + r) * 128 + cc];
  }
  if (tid < 4) {
    lds[L_AB0 + tid] = p.ab_ih0[tid * 128 + j] + p.ab_hh0[tid * 128 + j];
    lds[L_AB1 + tid] = p.ab_ih1[tid * 128 + j] + p.ab_hh1[tid * 128 + j];
    lds[L_FB0 + tid] = p.fb0[j * 4 + tid];
    lds[L_FB1 + tid] = p.fb1[j * 4 + tid];
  }
  if (tid < 20) {
    lds[L_PB0 + tid] = p.pb0[j * 20 + tid];
    lds[L_PB1 + tid] = p.pb1[j * 20 + tid];
  }
  for (int i = wgid * NTHR + tid; i < WS_ZERO_END; i += NWG * NTHR) ws[i] = 0.f;

  int e = 1;
  bar_arrive(bar, e, tid, wgid);
  bar_wait(bar, e, tid, wgid);

  const int b32 = tid >> 4;
  const int q   = (tid >> 2) & 3;
  const int ks  = tid & 3;
  const int b   = h * 32 + b32;
  const int lane = tid & 63;
  const bool cell = (tid & 15) == 0;
  const bool ks0  = (tid & 3) == 0;

  // initial pre0 for t=0 (states are zero, x(0) known)
  const float* w0r = lds + L_AWX0 + (q * 4 + ks) * 324;
  const float* w1r = lds + L_AWX1 + (q * 4 + ks) * 324;
  float pre0;
  {
    const float* xt0 = p.x;
    float s = dot_q(xt0 + b * 512 + ks * 128, w0r, 32);
    s += dot_q(ws + O_FHX0 + b * 512 + ks * 128, w0r + 128, 32);
    s += dot_q(ws + O_AHX0 + b * 128 + ks * 32,  w0r + 288, 8);
    pre0 = s;
  }

  for (int t = 0; t < TT; ++t) {
    const int old = t & 1, nw = old ^ 1;
    float* ahx0_o = ws + O_AHX0 + old * 8192;
    float* ahx0_n = ws + O_AHX0 + nw  * 8192;
    float* ahx1_o = ws + O_AHX1 + old * 8192;
    float* ahx1_n = ws + O_AHX1 + nw  * 8192;
    float* ahc0   = ws + O_AHC0;
    float* ahc1   = ws + O_AHC1;
    float* fhx0_o = ws + O_FHX0 + old * 32768;
    float* fhx0_n = ws + O_FHX0 + nw  * 32768;
    float* fhx1_o = ws + O_FHX1 + old * 32768;
    float* fhx1_n = ws + O_FHX1 + nw  * 32768;
    float* pol0   = ws + O_POL0;
    float* pol1   = ws + O_POL1;
    const float* xt = p.x + (size_t)t * 64 * 512;

    // ---- P0: LSTM0 residual (ahx1 part) + gate finish ----
    {
      float s = pre0 + dot_q(ahx1_o + b * 128 + ks * 32, w0r + 256, 8);
      s += __shfl_xor(s, 1); s += __shfl_xor(s, 2);
      float gi = __shfl(s, (lane & 48) + 0),  gf = __shfl(s, (lane & 48) + 4);
      float gg = __shfl(s, (lane & 48) + 8),  go = __shfl(s, (lane & 48) + 12);
      if (cell) {
        gi += lds[L_AB0 + 0]; gf += lds[L_AB0 + 1];
        gg += lds[L_AB0 + 2]; go += lds[L_AB0 + 3];
        float c  = ahc0[b * 128 + j];
        float c2 = sigm(gf) * c + sigm(gi) * tanhf(gg);
        ahc0[b * 128 + j]   = c2;
        ahx0_n[b * 128 + j] = sigm(go) * tanhf(c2);
      }
    }
    ++e; bar_arrive(bar, e, tid, wgid); bar_wait(bar, e, tid, wgid);   // B1

    // ---- P1: pol0 rows 20j..20j+19 ----
    for (int idx = tid; idx < 640; idx += NTHR) {
      int r = idx >> 5, bb = h * 32 + (idx & 31);
      pol0[bb * 2560 + j * 20 + r] = lds[L_PB0 + r] +
          dot_q(ahx0_n + bb * 128, lds + L_PW0 + r * 132, 32);
    }
    ++e; bar_arrive(bar, e, tid, wgid); bar_wait(bar, e, tid, wgid);   // B2

    // ---- P2: aRNN0 ----
    {
      const float* wi = lds + L_FWI0 + (q * 4 + ks) * 132;
      const float* wh = lds + L_FWH0 + (q * 4 + ks) * 132;
      const float* pr = pol0 + b * 2560;
      float sig = dot3_q(xt     + b * 512 + ks * 128, pr +       ks * 128, wi, 32);
      float shg = dot3_q(fhx0_o + b * 512 + ks * 128, pr + 512 + ks * 128, wh, 32);
      sig += __shfl_xor(sig, 1); sig += __shfl_xor(sig, 2);
      shg += __shfl_xor(shg, 1); shg += __shfl_xor(shg, 2);
      if (ks0) {
        int c = j * 4 + q;
        float v = tanhf(sig * pr[1024 + c] + lds[L_FB0 + q] * pr[2048 + c] + shg * pr[1536 + c]);
        fhx0_n[b * 512 + c] = v;
      }
    }
    ++e; bar_arrive(bar, e, tid, wgid);                                // B3 arrive
    // window: LSTM1 partials independent of P2
    float pre3;
    {
      float s = dot_q(fhx1_o + b * 512 + ks * 128, w1r + 128, 32);
      s += dot_q(ahx0_n + b * 128 + ks * 32, w1r + 256, 8);
      s += dot_q(ahx1_o + b * 128 + ks * 32, w1r + 288, 8);
      pre3 = s;
    }
    bar_wait(bar, e, tid, wgid);                                       // B3 wait

    // ---- P3: LSTM1 residual (fhx0_n part) + gate finish ----
    {
      float s = pre3 + dot_q(fhx0_n + b * 512 + ks * 128, w1r, 32);
      s += __shfl_xor(s, 1); s += __shfl_xor(s, 2);
      float gi = __shfl(s, (lane & 48) + 0),  gf = __shfl(s, (lane & 48) + 4);
      float gg = __shfl(s, (lane & 48) + 8),  go = __shfl(s, (lane & 48) + 12);
      if (cell) {
        gi += lds[L_AB1 + 0]; gf += lds[L_AB1 + 1];
        gg += lds[L_AB1 + 2]; go += lds[L_AB1 + 3];
        float c  = ahc1[b * 128 + j];
        float c2 = sigm(gf) * c + sigm(gi) * tanhf(gg);
        ahc1[b * 128 + j]   = c2;
        ahx1_n[b * 128 + j] = sigm(go) * tanhf(c2);
      }
    }
    ++e; bar_arrive(bar, e, tid, wgid); bar_wait(bar, e, tid, wgid);   // B4

    // ---- P4: pol1 ----
    for (int idx = tid; idx < 640; idx += NTHR) {
      int r = idx >> 5, bb = h * 32 + (idx & 31);
      pol1[bb * 2560 + j * 20 + r] = lds[L_PB1 + r] +
          dot_q(ahx1_n + bb * 128, lds + L_PW1 + r * 132, 32);
    }
    ++e; bar_arrive(bar, e, tid, wgid);                                // B5 arrive
    // window: next step's LSTM0 partials
    if (t + 1 < TT) {
      const float* xn = p.x + (size_t)(t + 1) * 64 * 512;
      float s = dot_q(xn + b * 512 + ks * 128, w0r, 32);
      s += dot_q(fhx0_n + b * 512 + ks * 128, w0r + 128, 32);
      s += dot_q(ahx0_n + b * 128 + ks * 32,  w0r + 288, 8);
      pre0 = s;
    }
    bar_wait(bar, e, tid, wgid);                                       // B5 wait

    // ---- P5: aRNN1 + output (no trailing barrier; P0(t+1) hazard-free vs P5) ----
    {
      const float* wi = lds + L_FWI1 + (q * 4 + ks) * 132;
      const float* wh = lds + L_FWH1 + (q * 4 + ks) * 132;
      const float* pr = pol1 + b * 2560;
      float sig = dot3_q(fhx0_n + b * 512 + ks * 128, pr +       ks * 128, wi, 32);
      float shg = dot3_q(fhx1_o + b * 512 + ks * 128, pr + 512 + ks * 128, wh, 32);
      sig += __shfl_xor(sig, 1); sig += __shfl_xor(sig, 2);
      shg += __shfl_xor(shg, 1); shg += __shfl_xor(shg, 2);
      if (ks0) {
        int c = j * 4 + q;
        float v = tanhf(sig * pr[1024 + c] + lds[L_FB1 + q] * pr[2048 + c] + shg * pr[1536 + c]);
        fhx1_n[b * 512 + c] = v;
        p.out[((size_t)t * 64 + b) * 512 + c] = v;
      }
    }
  }
}

extern "C" void kernel_launch(void* const* d_in, const int* in_sizes, int n_in,
                              void* d_out, int out_size, void* d_ws, size_t ws_size,
                              hipStream_t stream) {
  Params prm;
  prm.x      = (const float*)d_in[0];
  prm.aW_ih0 = (const float*)d_in[1];
  prm.aW_hh0 = (const float*)d_in[2];
  prm.ab_ih0 = (const float*)d_in[3];
  prm.ab_hh0 = (const float*)d_in[4];
  prm.pW0    = (const float*)d_in[5];
  prm.pb0    = (const float*)d_in[6];
  prm.fW_ih0 = (const float*)d_in[7];
  prm.fW_hh0 = (const float*)d_in[8];
  prm.fb0    = (const float*)d_in[9];
  prm.aW_ih1 = (const float*)d_in[10];
  prm.aW_hh1 = (const float*)d_in[11];
  prm.ab_ih1 = (const float*)d_in[12];
  prm.ab_hh1 = (const float*)d_in[13];
  prm.pW1    = (const float*)d_in[14];
  prm.pb1    = (const float*)d_in[15];
  prm.fW_ih1 = (const float*)d_in[16];
  prm.fW_hh1 = (const float*)d_in[17];
  prm.fb1    = (const float*)d_in[18];
  prm.out    = (float*)d_out;
  prm.ws     = (float*)d_ws;

  // zero the barrier block (arrive counters + root epoch + group epochs)
  hipMemsetAsync((char*)d_ws + (size_t)O_BAR * 4, 0, 16384, stream);

  static int lds_bytes = LDS_F * 4;
  hipFuncSetAttribute((const void*)arnn_kernel,
                      hipFuncAttributeMaxDynamicSharedMemorySize, lds_bytes);

  void* kargs[] = { (void*)&prm };
  hipLaunchCooperativeKernel((const void*)arnn_kernel, dim3(NWG), dim3(NTHR),
                             kargs, lds_bytes, stream);
}

// Round 11
// 148111.536 us; speedup vs baseline: 1.7663x; 1.0583x over previous
//
#include <hip/hip_runtime.h>

#define TT    1024
#define NTHR  512
#define NWG   256

// ---------------- ws layout (float offsets) ----------------
#define O_AHX0 0               // 2 slots x 64*128
#define O_AHC0 16384           // 64*128
#define O_AHX1 24576           // 2 slots
#define O_AHC1 40960
#define O_FHX0 49152           // 2 slots x 64*512
#define O_FHX1 114688          // 2 slots
#define WS_ZERO_END 180224     // states only (pol fully written before read)
#define O_POL0 180224          // 2 slots x 64*2560
#define O_POL1 507904          // 2 slots x 64*2560
#define O_BAR  835584          // barrier ints, 16 KB, zeroed by hipMemsetAsync

// barrier int offsets: group arrive g*64 (g=0..15), root, root-epoch,
// per-group epoch lines
#define BI_ROOT   1024
#define BI_REPOCH 1088
#define BI_GEPOCH 1280

// ---------------- LDS layout (float offsets) ----------------
// AWX row (q*4+ks): [128 xseg | 128 hseg | 32 a-seg | 32 AU-seg], stride 324
#define L_AWX0 0               // 16*324
#define L_AWX1 5184
#define L_FWI0 10368           // 16*132 rows (c4*4+ks)
#define L_FWH0 12480
#define L_FWI1 14592
#define L_FWH1 16704
#define L_PW0  18816           // 20*132
#define L_PW1  21456
#define L_AB0  24096
#define L_AB1  24100
#define L_FB0  24104
#define L_FB1  24108
#define L_PB0  24112
#define L_PB1  24132
#define LDS_F  24152           // 96,608 B

__device__ __forceinline__ float sigm(float x) { return 1.f / (1.f + __expf(-x)); }

__device__ __forceinline__ float dot_q(const float* __restrict__ a,
                                       const float* __restrict__ w, int n4) {
  float s0 = 0.f, s1 = 0.f, s2 = 0.f, s3 = 0.f;
  #pragma unroll 8
  for (int k = 0; k < n4; ++k) {
    float4 av = ((const float4*)a)[k];
    float4 wv = ((const float4*)w)[k];
    s0 = fmaf(av.x, wv.x, s0); s1 = fmaf(av.y, wv.y, s1);
    s2 = fmaf(av.z, wv.z, s2); s3 = fmaf(av.w, wv.w, s3);
  }
  return (s0 + s1) + (s2 + s3);
}
__device__ __forceinline__ float dot3_q(const float* __restrict__ a,
                                        const float* __restrict__ p,
                                        const float* __restrict__ w, int n4) {
  float s0 = 0.f, s1 = 0.f, s2 = 0.f, s3 = 0.f;
  #pragma unroll 8
  for (int k = 0; k < n4; ++k) {
    float4 av = ((const float4*)a)[k];
    float4 pv = ((const float4*)p)[k];
    float4 wv = ((const float4*)w)[k];
    s0 = fmaf(av.x * pv.x, wv.x, s0); s1 = fmaf(av.y * pv.y, wv.y, s1);
    s2 = fmaf(av.z * pv.z, wv.z, s2); s3 = fmaf(av.w * pv.w, wv.w, s3);
  }
  return (s0 + s1) + (s2 + s3);
}

// ---- 2-level grid barrier (R5-proven arrive) + fan-out wakeup (R10-proven) ----
__device__ __forceinline__ void bar_arrive(int* bar, int e, int tid, int wid) {
  __syncthreads();
  if (tid == 0) {
    int g = wid & 15;
    int old = __hip_atomic_fetch_add(&bar[g * 64], 1,
                                     __ATOMIC_ACQ_REL, __HIP_MEMORY_SCOPE_AGENT);
    if (old == e * 16 - 1) {
      int rold = __hip_atomic_fetch_add(&bar[BI_ROOT], 1,
                                        __ATOMIC_ACQ_REL, __HIP_MEMORY_SCOPE_AGENT);
      if (rold == e * 16 - 1) {
        __hip_atomic_store(&bar[BI_REPOCH], e,
                           __ATOMIC_RELEASE, __HIP_MEMORY_SCOPE_AGENT);
      }
    }
  }
}
__device__ __forceinline__ void bar_wait(int* bar, int e, int tid, int wid) {
  if (tid == 0) {
    if (wid < 16) {
      while (__hip_atomic_load(&bar[BI_REPOCH], __ATOMIC_RELAXED,
                               __HIP_MEMORY_SCOPE_AGENT) < e)
        __builtin_amdgcn_s_sleep(1);
      (void)__hip_atomic_load(&bar[BI_REPOCH], __ATOMIC_ACQUIRE,
                              __HIP_MEMORY_SCOPE_AGENT);
      __hip_atomic_store(&bar[BI_GEPOCH + wid * 64], e,
                         __ATOMIC_RELEASE, __HIP_MEMORY_SCOPE_AGENT);
    } else {
      int g = wid & 15;
      while (__hip_atomic_load(&bar[BI_GEPOCH + g * 64], __ATOMIC_RELAXED,
                               __HIP_MEMORY_SCOPE_AGENT) < e)
        __builtin_amdgcn_s_sleep(1);
      (void)__hip_atomic_load(&bar[BI_GEPOCH + g * 64], __ATOMIC_ACQUIRE,
                              __HIP_MEMORY_SCOPE_AGENT);
    }
  }
  __syncthreads();
}

struct Params {
  const float* x;
  const float *aW_ih0, *aW_hh0, *ab_ih0, *ab_hh0, *pW0, *pb0, *fW_ih0, *fW_hh0, *fb0;
  const float *aW_ih1, *aW_hh1, *ab_ih1, *ab_hh1, *pW1, *pb1, *fW_ih1, *fW_hh1, *fb1;
  float* out;
  float* ws;
};

__global__ __launch_bounds__(NTHR, 1)
void arnn_kernel(Params p) {
  extern __shared__ float lds[];
  const int tid  = threadIdx.x;
  const int wgid = blockIdx.x;
  const int j    = wgid >> 1;          // unit 0..127
  const int h    = wgid & 1;           // batch half
  float* __restrict__ ws = p.ws;
  int* bar = (int*)(ws + O_BAR);

  // ---- preload weight slices (fp32) into LDS (R10-proven) ----
  for (int i = tid; i < 16 * 320; i += NTHR) {
    int rr = i / 320, cc = i - rr * 320;
    int q = rr >> 2, ks = rr & 3;
    size_t lrow = (size_t)(q * 128 + j) * 1152;
    size_t hrow = (size_t)(q * 128 + j) * 128;
    float v0, v1;
    if (cc < 128)      { v0 = p.aW_ih0[lrow + ks*128 + cc];           v1 = p.aW_ih1[lrow + ks*128 + cc]; }
    else if (cc < 256) { v0 = p.aW_ih0[lrow + 512 + ks*128 + cc-128]; v1 = p.aW_ih1[lrow + 512 + ks*128 + cc-128]; }
    else if (cc < 288) { v0 = p.aW_ih0[lrow + 1024 + ks*32 + cc-256]; v1 = p.aW_ih1[lrow + 1024 + ks*32 + cc-256]; }
    else               { v0 = p.aW_hh0[hrow + ks*32 + cc-288];        v1 = p.aW_hh1[hrow + ks*32 + cc-288]; }
    lds[L_AWX0 + rr * 324 + cc] = v0;
    lds[L_AWX1 + rr * 324 + cc] = v1;
  }
  for (int i = tid; i < 16 * 128; i += NTHR) {
    int rr = i >> 7, cc = i & 127, c4 = rr >> 2, ks = rr & 3;
    size_t srow = (size_t)(j * 4 + c4) * 512 + ks * 128 + cc;
    lds[L_FWI0 + rr * 132 + cc] = p.fW_ih0[srow];
    lds[L_FWH0 + rr * 132 + cc] = p.fW_hh0[srow];
    lds[L_FWI1 + rr * 132 + cc] = p.fW_ih1[srow];
    lds[L_FWH1 + rr * 132 + cc] = p.fW_hh1[srow];
  }
  for (int i = tid; i < 20 * 128; i += NTHR) {
    int r = i >> 7, cc = i & 127;
    lds[L_PW0 + r * 132 + cc] = p.pW0[(size_t)(j * 20 + r) * 128 + cc];
    lds[L_PW1 + r * 132 + cc] = p.pW1[(size_t)(j * 20 + r) * 128 + cc];
  }
  if (tid < 4) {
    lds[L_AB0 + tid] = p.ab_ih0[tid * 128 + j] + p.ab_hh0[tid * 128 + j];
    lds[L_AB1 + tid] = p.ab_ih1[tid * 128 + j] + p.ab_hh1[tid * 128 + j];
    lds[L_FB0 + tid] = p.fb0[j * 4 + tid];
    lds[L_FB1 + tid] = p.fb1[j * 4 + tid];
  }
  if (tid < 20) {
    lds[L_PB0 + tid] = p.pb0[j * 20 + tid];
    lds[L_PB1 + tid] = p.pb1[j * 20 + tid];
  }
  for (int i = wgid * NTHR + tid; i < WS_ZERO_END; i += NWG * NTHR) ws[i] = 0.f;

  int e = 1;
  bar_arrive(bar, e, tid, wgid);
  bar_wait(bar, e, tid, wgid);

  const int b32 = tid >> 4;
  const int q   = (tid >> 2) & 3;
  const int ks  = tid & 3;
  const int b   = h * 32 + b32;
  const int lane = tid & 63;
  const bool cell = (tid & 15) == 0;
  const bool ks0  = (tid & 3) == 0;

  const float* w0r = lds + L_AWX0 + (q * 4 + ks) * 324;
  const float* w1r = lds + L_AWX1 + (q * 4 + ks) * 324;

  // ---- startup S1: LSTM0(0) (all states zero -> x-term + bias only) ----
  {
    float s = dot_q(p.x + b * 512 + ks * 128, w0r, 32);
    s += __shfl_xor(s, 1); s += __shfl_xor(s, 2);
    float gi = __shfl(s, (lane & 48) + 0),  gf = __shfl(s, (lane & 48) + 4);
    float gg = __shfl(s, (lane & 48) + 8),  go = __shfl(s, (lane & 48) + 12);
    if (cell) {
      gi += lds[L_AB0 + 0]; gf += lds[L_AB0 + 1];
      gg += lds[L_AB0 + 2]; go += lds[L_AB0 + 3];
      float c2 = sigm(gi) * tanhf(gg);               // ahc0_prev = 0
      ws[O_AHC0 + b * 128 + j] = c2;
      ws[O_AHX0 + 8192 + b * 128 + j] = sigm(go) * tanhf(c2);   // ahx0(0) -> slot1
    }
  }
  ++e; bar_arrive(bar, e, tid, wgid); bar_wait(bar, e, tid, wgid);

  // ---- startup S2: pol0(0) -> pol0 slot0 ----
  for (int idx = tid; idx < 640; idx += NTHR) {
    int r = idx >> 5, bb = h * 32 + (idx & 31);
    ws[O_POL0 + bb * 2560 + j * 20 + r] = lds[L_PB0 + r] +
        dot_q(ws + O_AHX0 + 8192 + bb * 128, lds + L_PW0 + r * 132, 32);
  }
  ++e; bar_arrive(bar, e, tid, wgid); bar_wait(bar, e, tid, wgid);

  float pre0 = 0.f;
  for (int t = 0; t < TT; ++t) {
    const int old = t & 1, nw = old ^ 1;
    float* ahx0_A = ws + O_AHX0 + old * 8192;     // written in SP_C with ahx0(t+1)
    float* ahx0_n = ws + O_AHX0 + nw  * 8192;     // ahx0(t)
    float* ahx1_o = ws + O_AHX1 + old * 8192;     // ahx1(t-1)
    float* ahx1_n = ws + O_AHX1 + nw  * 8192;     // ahx1(t), written SP_B
    float* ahc0   = ws + O_AHC0;
    float* ahc1   = ws + O_AHC1;
    float* fhx0_o = ws + O_FHX0 + old * 32768;    // fhx0(t-1)
    float* fhx0_n = ws + O_FHX0 + nw  * 32768;    // fhx0(t), written SP_A
    float* fhx1_o = ws + O_FHX1 + old * 32768;    // fhx1(t-1)
    float* fhx1_n = ws + O_FHX1 + nw  * 32768;    // fhx1(t), written SP_D
    float* pol0s  = ws + O_POL0 + old * 163840;   // pol0(t)
    float* pol0n  = ws + O_POL0 + nw  * 163840;   // pol0(t+1), written SP_D
    float* pol1s  = ws + O_POL1 + old * 163840;   // pol1(t), written SP_C
    const float* xt = p.x + (size_t)t * 64 * 512;

    // ================= SP_A: aRNN0(t) =================
    {
      const float* wi = lds + L_FWI0 + (q * 4 + ks) * 132;
      const float* wh = lds + L_FWH0 + (q * 4 + ks) * 132;
      const float* pr = pol0s + b * 2560;
      float sig = dot3_q(xt     + b * 512 + ks * 128, pr +       ks * 128, wi, 32);
      float shg = dot3_q(fhx0_o + b * 512 + ks * 128, pr + 512 + ks * 128, wh, 32);
      sig += __shfl_xor(sig, 1); sig += __shfl_xor(sig, 2);
      shg += __shfl_xor(shg, 1); shg += __shfl_xor(shg, 2);
      if (ks0) {
        int c = j * 4 + q;
        float v = tanhf(sig * pr[1024 + c] + lds[L_FB0 + q] * pr[2048 + c] + shg * pr[1536 + c]);
        fhx0_n[b * 512 + c] = v;
      }
    }
    ++e; bar_arrive(bar, e, tid, wgid);                                // B_A arrive
    // window: LSTM1(t) partials independent of fhx0(t)
    float pre3;
    {
      float s = dot_q(fhx1_o + b * 512 + ks * 128, w1r + 128, 32);
      s += dot_q(ahx0_n + b * 128 + ks * 32, w1r + 256, 8);
      s += dot_q(ahx1_o + b * 128 + ks * 32, w1r + 288, 8);
      pre3 = s;
    }
    bar_wait(bar, e, tid, wgid);                                       // B_A wait

    // ================= SP_B: LSTM1(t) =================
    {
      float s = pre3 + dot_q(fhx0_n + b * 512 + ks * 128, w1r, 32);
      s += __shfl_xor(s, 1); s += __shfl_xor(s, 2);
      float gi = __shfl(s, (lane & 48) + 0),  gf = __shfl(s, (lane & 48) + 4);
      float gg = __shfl(s, (lane & 48) + 8),  go = __shfl(s, (lane & 48) + 12);
      if (cell) {
        gi += lds[L_AB1 + 0]; gf += lds[L_AB1 + 1];
        gg += lds[L_AB1 + 2]; go += lds[L_AB1 + 3];
        float c  = ahc1[b * 128 + j];
        float c2 = sigm(gf) * c + sigm(gi) * tanhf(gg);
        ahc1[b * 128 + j]   = c2;
        ahx1_n[b * 128 + j] = sigm(go) * tanhf(c2);
      }
    }
    ++e; bar_arrive(bar, e, tid, wgid);                                // B_B arrive
    // window: LSTM0(t+1) partials independent of ahx1(t)
    if (t + 1 < TT) {
      const float* xn = p.x + (size_t)(t + 1) * 64 * 512;
      float s = dot_q(xn + b * 512 + ks * 128, w0r, 32);
      s += dot_q(fhx0_n + b * 512 + ks * 128, w0r + 128, 32);   // fhx0(t)
      s += dot_q(ahx0_n + b * 128 + ks * 32,  w0r + 288, 8);    // ahx0(t)
      pre0 = s;
    }
    bar_wait(bar, e, tid, wgid);                                       // B_B wait

    // ================= SP_C: LSTM0(t+1) finish || pol1(t) =================
    if (t + 1 < TT) {
      float s = pre0 + dot_q(ahx1_n + b * 128 + ks * 32, w0r + 256, 8);  // ahx1(t)
      s += __shfl_xor(s, 1); s += __shfl_xor(s, 2);
      float gi = __shfl(s, (lane & 48) + 0),  gf = __shfl(s, (lane & 48) + 4);
      float gg = __shfl(s, (lane & 48) + 8),  go = __shfl(s, (lane & 48) + 12);
      if (cell) {
        gi += lds[L_AB0 + 0]; gf += lds[L_AB0 + 1];
        gg += lds[L_AB0 + 2]; go += lds[L_AB0 + 3];
        float c  = ahc0[b * 128 + j];
        float c2 = sigm(gf) * c + sigm(gi) * tanhf(gg);
        ahc0[b * 128 + j]   = c2;
        ahx0_A[b * 128 + j] = sigm(go) * tanhf(c2);              // ahx0(t+1) -> slot[old]
      }
    }
    for (int idx = tid; idx < 640; idx += NTHR) {
      int r = idx >> 5, bb = h * 32 + (idx & 31);
      pol1s[bb * 2560 + j * 20 + r] = lds[L_PB1 + r] +
          dot_q(ahx1_n + bb * 128, lds + L_PW1 + r * 132, 32);
    }
    ++e; bar_arrive(bar, e, tid, wgid); bar_wait(bar, e, tid, wgid);   // B_C

    // ================= SP_D: aRNN1(t)+out || pol0(t+1) =================
    {
      const float* wi = lds + L_FWI1 + (q * 4 + ks) * 132;
      const float* wh = lds + L_FWH1 + (q * 4 + ks) * 132;
      const float* pr = pol1s + b * 2560;
      float sig = dot3_q(fhx0_n + b * 512 + ks * 128, pr +       ks * 128, wi, 32);
      float shg = dot3_q(fhx1_o + b * 512 + ks * 128, pr + 512 + ks * 128, wh, 32);
      sig += __shfl_xor(sig, 1); sig += __shfl_xor(sig, 2);
      shg += __shfl_xor(shg, 1); shg += __shfl_xor(shg, 2);
      if (ks0) {
        int c = j * 4 + q;
        float v = tanhf(sig * pr[1024 + c] + lds[L_FB1 + q] * pr[2048 + c] + shg * pr[1536 + c]);
        fhx1_n[b * 512 + c] = v;
        p.out[((size_t)t * 64 + b) * 512 + c] = v;
      }
    }
    if (t + 1 < TT) {
      for (int idx = tid; idx < 640; idx += NTHR) {
        int r = idx >> 5, bb = h * 32 + (idx & 31);
        pol0n[bb * 2560 + j * 20 + r] = lds[L_PB0 + r] +
            dot_q(ahx0_A + bb * 128, lds + L_PW0 + r * 132, 32);   // ahx0(t+1)
      }
    }
    ++e; bar_arrive(bar, e, tid, wgid); bar_wait(bar, e, tid, wgid);   // B_D
  }
}

extern "C" void kernel_launch(void* const* d_in, const int* in_sizes, int n_in,
                              void* d_out, int out_size, void* d_ws, size_t ws_size,
                              hipStream_t stream) {
  Params prm;
  prm.x      = (const float*)d_in[0];
  prm.aW_ih0 = (const float*)d_in[1];
  prm.aW_hh0 = (const float*)d_in[2];
  prm.ab_ih0 = (const float*)d_in[3];
  prm.ab_hh0 = (const float*)d_in[4];
  prm.pW0    = (const float*)d_in[5];
  prm.pb0    = (const float*)d_in[6];
  prm.fW_ih0 = (const float*)d_in[7];
  prm.fW_hh0 = (const float*)d_in[8];
  prm.fb0    = (const float*)d_in[9];
  prm.aW_ih1 = (const float*)d_in[10];
  prm.aW_hh1 = (const float*)d_in[11];
  prm.ab_ih1 = (const float*)d_in[12];
  prm.ab_hh1 = (const float*)d_in[13];
  prm.pW1    = (const float*)d_in[14];
  prm.pb1    = (const float*)d_in[15];
  prm.fW_ih1 = (const float*)d_in[16];
  prm.fW_hh1 = (const float*)d_in[17];
  prm.fb1    = (const float*)d_in[18];
  prm.out    = (float*)d_out;
  prm.ws     = (float*)d_ws;

  // zero the barrier block (arrive counters + root epoch + group epochs)
  hipMemsetAsync((char*)d_ws + (size_t)O_BAR * 4, 0, 16384, stream);

  static int lds_bytes = LDS_F * 4;
  hipFuncSetAttribute((const void*)arnn_kernel,
                      hipFuncAttributeMaxDynamicSharedMemorySize, lds_bytes);

  void* kargs[] = { (void*)&prm };
  hipLaunchCooperativeKernel((const void*)arnn_kernel, dim3(NWG), dim3(NTHR),
                             kargs, lds_bytes, stream);
}

// Round 12
// 98067.316 us; speedup vs baseline: 2.6677x; 1.5103x over previous
//
#include <hip/hip_runtime.h>

#define TT    1024
#define NTHR  512
#define NWG   256

// ---- per-XCD state block (float offsets within block) ----
#define XB_SZ  65536           // floats per XCD (256 KB)
#define XA0    0               // ahx0: 2 x 8 x 128
#define XA1    2048            // ahx1: 2 x 8 x 128
#define XF0    4096            // fhx0: 2 x 8 x 512
#define XF1    12288           // fhx1: 2 x 8 x 512
#define XP0    20480           // pol0: 8 x 2560
#define XP1    40960           // pol1: 8 x 2560
#define X_ZERO_END 20480       // zero ahx/fhx only (pol written before read)

#define O_BARB (8 * XB_SZ)     // barrier block float offset (byte 2,097,152)
// bar ints: cnt[xcd]=xcd*256, epoch[xcd]=xcd*256+64, roster[xcd]=2048+xcd

__device__ __forceinline__ float sigm(float x) { return 1.f / (1.f + __expf(-x)); }

// K-sliced dot: thread ks takes float4 #(k*4+ks) -> 4 lanes (ks=0..3) read
// 64B-contiguous chunks (coalesced); slices are disjoint and complete.
__device__ __forceinline__ float dot_ks(const float* __restrict__ a,
                                        const float* __restrict__ w,
                                        int nq, int ks) {
  float s0=0.f,s1=0.f,s2=0.f,s3=0.f;
  const float4* a4=(const float4*)a; const float4* w4=(const float4*)w;
  #pragma unroll 8
  for (int k = 0; k < nq; ++k) {
    int i4 = (k<<2) + ks;
    float4 av = a4[i4], wv = w4[i4];
    s0=fmaf(av.x,wv.x,s0); s1=fmaf(av.y,wv.y,s1);
    s2=fmaf(av.z,wv.z,s2); s3=fmaf(av.w,wv.w,s3);
  }
  return (s0+s1)+(s2+s3);
}
__device__ __forceinline__ float dot3_ks(const float* __restrict__ a,
                                         const float* __restrict__ pp,
                                         const float* __restrict__ w,
                                         int nq, int ks) {
  float s0=0.f,s1=0.f,s2=0.f,s3=0.f;
  const float4* a4=(const float4*)a; const float4* p4=(const float4*)pp;
  const float4* w4=(const float4*)w;
  #pragma unroll 8
  for (int k = 0; k < nq; ++k) {
    int i4 = (k<<2) + ks;
    float4 av = a4[i4], pv = p4[i4], wv = w4[i4];
    s0=fmaf(av.x*pv.x,wv.x,s0); s1=fmaf(av.y*pv.y,wv.y,s1);
    s2=fmaf(av.z*pv.z,wv.z,s2); s3=fmaf(av.w*pv.w,wv.w,s3);
  }
  return (s0+s1)+(s2+s3);
}
__device__ __forceinline__ float dot_full(const float* __restrict__ a,
                                          const float* __restrict__ w) {
  float s0=0.f,s1=0.f,s2=0.f,s3=0.f;
  const float4* a4=(const float4*)a; const float4* w4=(const float4*)w;
  #pragma unroll 8
  for (int k = 0; k < 32; ++k) {
    float4 av = a4[k], wv = w4[k];
    s0=fmaf(av.x,wv.x,s0); s1=fmaf(av.y,wv.y,s1);
    s2=fmaf(av.z,wv.z,s2); s3=fmaf(av.w,wv.w,s3);
  }
  return (s0+s1)+(s2+s3);
}

// ---- intra-XCD barrier: NO release fence (peers share this XCD's L2).
// Producer stores drain to L2 at __syncthreads (per-wave vmcnt); relaxed RMW /
// epoch store issue after and serialize at the coherence point. Consumer polls
// relaxed, then ONE acquire load (buffer_inv drops clean lines; same-L2 dirty
// data survives), then reads data from the shared L2.
__device__ __forceinline__ void xbar(int* cnt, int* ep, int e, int tid) {
  __syncthreads();
  if (tid == 0) {
    int old = __hip_atomic_fetch_add(cnt, 1, __ATOMIC_RELAXED,
                                     __HIP_MEMORY_SCOPE_AGENT);
    if (old == e * 32 - 1)
      __hip_atomic_store(ep, e, __ATOMIC_RELAXED, __HIP_MEMORY_SCOPE_AGENT);
    while (__hip_atomic_load(ep, __ATOMIC_RELAXED,
                             __HIP_MEMORY_SCOPE_AGENT) < e)
      __builtin_amdgcn_s_sleep(1);
    (void)__hip_atomic_load(ep, __ATOMIC_ACQUIRE, __HIP_MEMORY_SCOPE_AGENT);
  }
  __syncthreads();
}

struct Params {
  const float* x;
  const float *aW_ih0, *aW_hh0, *ab_ih0, *ab_hh0, *pW0, *pb0, *fW_ih0, *fW_hh0, *fb0;
  const float *aW_ih1, *aW_hh1, *ab_ih1, *ab_hh1, *pW1, *pb1, *fW_ih1, *fW_hh1, *fb1;
  float* out;
  float* ws;
};

__global__ __launch_bounds__(NTHR, 1)
void arnn_kernel(Params p) {
  extern __shared__ float lds[];     // dummy 84 KB: forces 1 WG/CU (pigeonhole)
  __shared__ int s_rank;
  const int tid = threadIdx.x;
  float* __restrict__ ws = p.ws;

  int xcd;
  asm volatile("s_getreg_b32 %0, hwreg(HW_REG_XCC_ID)" : "=s"(xcd));
  xcd &= 7;

  int* bar = (int*)(ws + O_BARB);
  if (tid == 0)
    s_rank = __hip_atomic_fetch_add(&bar[2048 + xcd], 1,
                                    __ATOMIC_RELAXED, __HIP_MEMORY_SCOPE_AGENT);
  __syncthreads();
  const int r = s_rank;              // rank 0..31 within this XCD
  int* cnt = &bar[xcd * 256];
  int* ep  = &bar[xcd * 256 + 64];

  float* xb = ws + (size_t)xcd * XB_SZ;
  const int b0 = xcd * 8;            // this XCD owns batches b0..b0+7

  // zero this XCD's recurrent state
  for (int i = r * NTHR + tid; i < X_ZERO_END; i += 32 * NTHR) xb[i] = 0.f;

  // ---- thread maps ----
  const int lane = tid & 63;
  const int ks   = tid & 3;
  // LSTM: jj(2b) bl(3b) q(2b) ks(2b)
  const int jj = tid >> 7, blL = (tid >> 4) & 7, q = (tid >> 2) & 3;
  const int jL = r * 4 + jj;
  const bool cell = (tid & 15) == 0;
  // aRNN: c4(4b) bl(3b) ks(2b)
  const int c4 = tid >> 5, blA = (tid >> 2) & 7;
  const int cA = r * 16 + c4;
  // pol: item idx = col(>>3) | bl(&7); 640 items = tid pass + (tid+512, tid<128)
  const int nA = r * 80 + (tid >> 3), blP = tid & 7;
  const int nB = r * 80 + 64 + (tid >> 3);      // valid if tid < 128

  // ---- bias preloads (registers) ----
  float bi0=0,bf0=0,bg0=0,bo0=0, bi1=0,bf1=0,bg1=0,bo1=0;
  if (cell) {
    bi0 = p.ab_ih0[0*128+jL] + p.ab_hh0[0*128+jL];
    bf0 = p.ab_ih0[1*128+jL] + p.ab_hh0[1*128+jL];
    bg0 = p.ab_ih0[2*128+jL] + p.ab_hh0[2*128+jL];
    bo0 = p.ab_ih0[3*128+jL] + p.ab_hh0[3*128+jL];
    bi1 = p.ab_ih1[0*128+jL] + p.ab_hh1[0*128+jL];
    bf1 = p.ab_ih1[1*128+jL] + p.ab_hh1[1*128+jL];
    bg1 = p.ab_ih1[2*128+jL] + p.ab_hh1[2*128+jL];
    bo1 = p.ab_ih1[3*128+jL] + p.ab_hh1[3*128+jL];
  }
  const float fb0c = p.fb0[cA], fb1c = p.fb1[cA];
  const float pb0a = p.pb0[nA], pb1a = p.pb1[nA];
  float pb0b = 0.f, pb1b = 0.f;
  if (tid < 128) { pb0b = p.pb0[nB]; pb1b = p.pb1[nB]; }

  // ---- streamed weight row pointers ----
  const int rowL = q * 128 + jL;
  const float* wih0 = p.aW_ih0 + (size_t)rowL * 1152;
  const float* whh0 = p.aW_hh0 + (size_t)rowL * 128;
  const float* wih1 = p.aW_ih1 + (size_t)rowL * 1152;
  const float* whh1 = p.aW_hh1 + (size_t)rowL * 128;
  const float* fwi0 = p.fW_ih0 + (size_t)cA * 512;
  const float* fwh0 = p.fW_hh0 + (size_t)cA * 512;
  const float* fwi1 = p.fW_ih1 + (size_t)cA * 512;
  const float* fwh1 = p.fW_hh1 + (size_t)cA * 512;

  float creg0 = 0.f, creg1 = 0.f;    // LSTM cell states (thread-resident)

  int e = 1;
  xbar(cnt, ep, e, tid);

  for (int t = 0; t < TT; ++t) {
    const int old = t & 1, nw = old ^ 1;
    float* ahx0_o = xb + XA0 + old * 1024;
    float* ahx0_n = xb + XA0 + nw  * 1024;
    float* ahx1_o = xb + XA1 + old * 1024;
    float* ahx1_n = xb + XA1 + nw  * 1024;
    float* fhx0_o = xb + XF0 + old * 4096;
    float* fhx0_n = xb + XF0 + nw  * 4096;
    float* fhx1_o = xb + XF1 + old * 4096;
    float* fhx1_n = xb + XF1 + nw  * 4096;
    float* pol0   = xb + XP0;
    float* pol1   = xb + XP1;
    const float* xt = p.x + ((size_t)t * 64 + b0) * 512;

    // ---- P0: LSTM0 ----
    {
      float s = dot_ks(xt     + blL * 512, wih0,        32, ks)
              + dot_ks(fhx0_o + blL * 512, wih0 + 512,  32, ks)
              + dot_ks(ahx1_o + blL * 128, wih0 + 1024,  8, ks)
              + dot_ks(ahx0_o + blL * 128, whh0,         8, ks);
      s += __shfl_xor(s, 1); s += __shfl_xor(s, 2);
      float gi = __shfl(s,(lane&48)+0),  gf = __shfl(s,(lane&48)+4);
      float gg = __shfl(s,(lane&48)+8),  go = __shfl(s,(lane&48)+12);
      if (cell) {
        gi += bi0; gf += bf0; gg += bg0; go += bo0;
        float c2 = sigm(gf) * creg0 + sigm(gi) * tanhf(gg);
        creg0 = c2;
        ahx0_n[blL * 128 + jL] = sigm(go) * tanhf(c2);
      }
    }
    ++e; xbar(cnt, ep, e, tid);

    // ---- P1: pol0 ----
    {
      pol0[blP * 2560 + nA] = pb0a +
          dot_full(ahx0_n + blP * 128, p.pW0 + (size_t)nA * 128);
      if (tid < 128)
        pol0[blP * 2560 + nB] = pb0b +
            dot_full(ahx0_n + blP * 128, p.pW0 + (size_t)nB * 128);
    }
    ++e; xbar(cnt, ep, e, tid);

    // ---- P2: aRNN0 ----
    {
      const float* pr = pol0 + blA * 2560;
      float sig = dot3_ks(xt     + blA * 512, pr,       fwi0, 32, ks);
      float shg = dot3_ks(fhx0_o + blA * 512, pr + 512, fwh0, 32, ks);
      sig += __shfl_xor(sig, 1); sig += __shfl_xor(sig, 2);
      shg += __shfl_xor(shg, 1); shg += __shfl_xor(shg, 2);
      if (ks == 0) {
        float v = tanhf(sig * pr[1024 + cA] + fb0c * pr[2048 + cA]
                      + shg * pr[1536 + cA]);
        fhx0_n[blA * 512 + cA] = v;
      }
    }
    ++e; xbar(cnt, ep, e, tid);

    // ---- P3: LSTM1 ----
    {
      float s = dot_ks(fhx0_n + blL * 512, wih1,        32, ks)
              + dot_ks(fhx1_o + blL * 512, wih1 + 512,  32, ks)
              + dot_ks(ahx0_n + blL * 128, wih1 + 1024,  8, ks)
              + dot_ks(ahx1_o + blL * 128, whh1,         8, ks);
      s += __shfl_xor(s, 1); s += __shfl_xor(s, 2);
      float gi = __shfl(s,(lane&48)+0),  gf = __shfl(s,(lane&48)+4);
      float gg = __shfl(s,(lane&48)+8),  go = __shfl(s,(lane&48)+12);
      if (cell) {
        gi += bi1; gf += bf1; gg += bg1; go += bo1;
        float c2 = sigm(gf) * creg1 + sigm(gi) * tanhf(gg);
        creg1 = c2;
        ahx1_n[blL * 128 + jL] = sigm(go) * tanhf(c2);
      }
    }
    ++e; xbar(cnt, ep, e, tid);

    // ---- P4: pol1 ----
    {
      pol1[blP * 2560 + nA] = pb1a +
          dot_full(ahx1_n + blP * 128, p.pW1 + (size_t)nA * 128);
      if (tid < 128)
        pol1[blP * 2560 + nB] = pb1b +
            dot_full(ahx1_n + blP * 128, p.pW1 + (size_t)nB * 128);
    }
    ++e; xbar(cnt, ep, e, tid);

    // ---- P5: aRNN1 + output ----
    {
      const float* pr = pol1 + blA * 2560;
      float sig = dot3_ks(fhx0_n + blA * 512, pr,       fwi1, 32, ks);
      float shg = dot3_ks(fhx1_o + blA * 512, pr + 512, fwh1, 32, ks);
      sig += __shfl_xor(sig, 1); sig += __shfl_xor(sig, 2);
      shg += __shfl_xor(shg, 1); shg += __shfl_xor(shg, 2);
      if (ks == 0) {
        float v = tanhf(sig * pr[1024 + cA] + fb1c * pr[2048 + cA]
                      + shg * pr[1536 + cA]);
        fhx1_n[blA * 512 + cA] = v;
        p.out[((size_t)t * 64 + b0 + blA) * 512 + cA] = v;
      }
    }
    ++e; xbar(cnt, ep, e, tid);
  }
  (void)lds;
}

extern "C" void kernel_launch(void* const* d_in, const int* in_sizes, int n_in,
                              void* d_out, int out_size, void* d_ws, size_t ws_size,
                              hipStream_t stream) {
  Params prm;
  prm.x      = (const float*)d_in[0];
  prm.aW_ih0 = (const float*)d_in[1];
  prm.aW_hh0 = (const float*)d_in[2];
  prm.ab_ih0 = (const float*)d_in[3];
  prm.ab_hh0 = (const float*)d_in[4];
  prm.pW0    = (const float*)d_in[5];
  prm.pb0    = (const float*)d_in[6];
  prm.fW_ih0 = (const float*)d_in[7];
  prm.fW_hh0 = (const float*)d_in[8];
  prm.fb0    = (const float*)d_in[9];
  prm.aW_ih1 = (const float*)d_in[10];
  prm.aW_hh1 = (const float*)d_in[11];
  prm.ab_ih1 = (const float*)d_in[12];
  prm.ab_hh1 = (const float*)d_in[13];
  prm.pW1    = (const float*)d_in[14];
  prm.pb1    = (const float*)d_in[15];
  prm.fW_ih1 = (const float*)d_in[16];
  prm.fW_hh1 = (const float*)d_in[17];
  prm.fb1    = (const float*)d_in[18];
  prm.out    = (float*)d_out;
  prm.ws     = (float*)d_ws;

  // zero barrier counters/epochs/roster (per launch -> deterministic replays)
  hipMemsetAsync((char*)d_ws + (size_t)O_BARB * 4, 0, 16384, stream);

  static int lds_bytes = 84 * 1024;   // forces 1 WG/CU (2x84 > 160 KB)
  hipFuncSetAttribute((const void*)arnn_kernel,
                      hipFuncAttributeMaxDynamicSharedMemorySize, lds_bytes);

  void* kargs[] = { (void*)&prm };
  hipLaunchCooperativeKernel((const void*)arnn_kernel, dim3(NWG), dim3(NTHR),
                             kargs, lds_bytes, stream);
}